// Round 7
// baseline (187.554 us; speedup 1.0000x reference)
//
#include <hip/hip_runtime.h>
#include <math.h>

#define N_NODES 10000
#define N_EDGES 640000
#define K_DIM   128     // IN_CH == HID == 128
#define OUT_CH  64
#define ELLW    192     // max in-degree slots; Poisson(64) max ~110, P[>192]~1e-19

#define CHUNKS  128
#define CHUNK_E 5000    // N_EDGES / CHUNKS exactly
#define GB      313     // ceil(10000/32) gemm blocks

typedef unsigned long long ull;
typedef unsigned int uint;
typedef unsigned short ushort;
typedef unsigned char uchar;

#define FIXED_SCALE 262144.0f   // 2^18; count<<24 | fixed18(sum_w)

// ---------------- workspace layout (bytes) ----------------
// xw1b     : N*128 bf16   @ 0            (2,560,000)
// h        : N*128 f32    @  2,560,000   (5,120,000)
// xw2b     : N*64  bf16   @  7,680,000   (1,280,000)
// epack    : N*ELLW ull   @  8,960,000   (15,360,000)  (nrm_bits<<32 | src)
// blockcnt : CHUNKS*N u32 @ 24,320,000   (5,120,000)   (cnt<<24 | fixed18(sum_w))
// base8    : CHUNKS*N u8  @ 29,440,000   (1,280,000)
// rank8    : E u8         @ 30,720,000   (640,000)
// sd32     : E u32        @ 31,360,000   (2,560,000)   (dst<<16 | src)
// cnt_arr  : N int        @ 33,920,000   (40,000)
// dinv     : N f32        @ 33,960,000   (40,000)

__device__ __forceinline__ float bf2f(ushort u) {
    return __uint_as_float(((uint)u) << 16);
}
__device__ __forceinline__ float bf_lo(uint u) {        // channel 2l (low ushort)
    return __uint_as_float(u << 16);
}
__device__ __forceinline__ float bf_hi(uint u) {        // channel 2l+1 (high ushort)
    return __uint_as_float(u & 0xffff0000u);
}
__device__ __forceinline__ ushort f2bf(float v) {
    uint u = __float_as_uint(v);
    uint r = u + 0x7fffu + ((u >> 16) & 1u);   // round-to-nearest-even
    return (ushort)(r >> 16);
}

// GEMM body: C_bf16[M,NCOL] = A[M,128] @ B[128,NCOL], fp32 accumulate.
template <int NCOL>
__device__ void gemm_body(const float* __restrict__ A, const float* __restrict__ B,
                          ushort* __restrict__ C, int blk, int M,
                          float* sA /*[32][33]*/, float* sB /*[32][NCOL]*/) {
    constexpr int K = 128;
    constexpr int TM = 32;
    constexpr int KT = 32;
    constexpr int R = 256 / NCOL;   // 2 (NCOL=128) or 4 (NCOL=64)
    constexpr int RPT = TM / R;     // 16 or 8
    int tid = threadIdx.x;
    int c = tid % NCOL;
    int rr = tid / NCOL;
    int row0 = blk * TM;
    float acc[RPT];
#pragma unroll
    for (int r = 0; r < RPT; ++r) acc[r] = 0.0f;

    for (int k0 = 0; k0 < K; k0 += KT) {
        for (int i = tid; i < TM * KT; i += 256) {
            int r = i / KT, k = i % KT;
            int gr = row0 + r;
            sA[r * (KT + 1) + k] = (gr < M) ? A[gr * K + k0 + k] : 0.0f;
        }
        for (int i = tid; i < KT * NCOL; i += 256) {
            int k = i / NCOL, cc = i % NCOL;
            sB[k * NCOL + cc] = B[(k0 + k) * NCOL + cc];
        }
        __syncthreads();
#pragma unroll
        for (int k = 0; k < KT; ++k) {
            float b = sB[k * NCOL + c];
#pragma unroll
            for (int r = 0; r < RPT; ++r)
                acc[r] += sA[(rr * RPT + r) * (KT + 1) + k] * b;
        }
        __syncthreads();
    }
#pragma unroll
    for (int r = 0; r < RPT; ++r) {
        int gr = row0 + rr * RPT + r;
        if (gr < M) C[gr * NCOL + c] = f2bf(acc[r]);
    }
}

// Kernel A. Blocks [0,CHUNKS): per-chunk u32 LDS counting histogram (no global
// atomics). Blocks [CHUNKS,..): gemm1 overlapped in the same launch.
__global__ __launch_bounds__(256) void preA_gemm1_kernel(const int* __restrict__ ei,
                                                         const float* __restrict__ ew,
                                                         uchar* __restrict__ rank8,
                                                         uint* __restrict__ sd32,
                                                         uint* __restrict__ blockcnt,
                                                         const float* __restrict__ x,
                                                         const float* __restrict__ W1,
                                                         ushort* __restrict__ xw1b) {
    __shared__ uint smem[N_NODES];   // 40 KB; gemm blocks overlay sA/sB here
    if (blockIdx.x < CHUNKS) {
        const int c = blockIdx.x;
        const int tid = threadIdx.x;
        __shared__ int sflag;
        if (tid == 0) sflag = 0;
        for (int i = tid; i < N_NODES; i += 256) smem[i] = 0u;
        __syncthreads();
        int a = (tid < 64) ? ei[2 * (c * CHUNK_E + tid) + 1] : 0;
        if (a) atomicOr(&sflag, 1);
        __syncthreads();
        const int f = sflag;                     // 1 => int32 layout
        const ull* ei64 = (const ull*)ei;
        for (int k = tid; k < CHUNK_E; k += 256) {
            int e = c * CHUNK_E + k;
            int s, d;
            if (f) { s = ei[e];        d = ei[N_EDGES + e]; }
            else   { s = (int)ei64[e]; d = (int)ei64[N_EDGES + e]; }
            float w = ew[e];
            uint fx = (uint)(w * FIXED_SCALE + 0.5f);
            uint old = atomicAdd(&smem[d], (1u << 24) | fx);
            rank8[e] = (uchar)(old >> 24);
            sd32[e] = ((uint)d << 16) | (uint)s;
        }
        __syncthreads();
        for (int i = tid; i < N_NODES; i += 256)
            blockcnt[c * N_NODES + i] = smem[i];
    } else {
        float* sA = (float*)smem;
        float* sB = sA + 32 * 33;
        gemm_body<128>(x, W1, xw1b, blockIdx.x - CHUNKS, N_NODES, sA, sB);
    }
}

// Kernel B: thread-per-node serial scan over the 128 chunk histograms.
__global__ __launch_bounds__(256) void scanB_kernel(const uint* __restrict__ blockcnt,
                                                    uchar* __restrict__ base8,
                                                    int* __restrict__ cnt_arr,
                                                    float* __restrict__ dinv) {
    int n = blockIdx.x * 256 + threadIdx.x;
    if (n >= N_NODES) return;
    uint wsum = 0;
    int run = 0;
#pragma unroll 8
    for (int c = 0; c < CHUNKS; ++c) {
        uint v = blockcnt[c * N_NODES + n];
        base8[c * N_NODES + n] = (uchar)run;
        run += (int)(v >> 24);
        wsum += v & 0xffffffu;
    }
    cnt_arr[n] = run;
    float dg = 1.0f + (float)wsum * (1.0f / FIXED_SCALE);
    dinv[n] = (float)(1.0 / sqrt((double)dg));
}

// Kernel C: atomic-free ELL fill. slot = base8[chunk][dst] + rank8[e].
#define FILL_SPLIT 4
#define FILL_PART  (CHUNK_E / FILL_SPLIT)   // 1250
__global__ __launch_bounds__(256) void fillC_kernel(const uint* __restrict__ sd32,
                                                    const float* __restrict__ ew,
                                                    const uchar* __restrict__ rank8,
                                                    const uchar* __restrict__ base8,
                                                    const float* __restrict__ dinv,
                                                    ull* __restrict__ epack) {
    const int c = blockIdx.x / FILL_SPLIT;
    const int p = blockIdx.x % FILL_SPLIT;
    const int k0 = p * FILL_PART;
    for (int k = k0 + threadIdx.x; k < k0 + FILL_PART; k += 256) {
        int e = c * CHUNK_E + k;
        uint sd = sd32[e];
        int s = (int)(sd & 0xffffu);
        int d = (int)(sd >> 16);
        float nrm = dinv[s] * ew[e] * dinv[d];
        int slot = (int)base8[c * N_NODES + d] + (int)rank8[e];
        if (slot < ELLW)
            epack[d * ELLW + slot] = ((ull)__float_as_uint(nrm) << 32) | (ull)(uint)s;
    }
}

__global__ __launch_bounds__(256) void gemm2_kernel(const float* __restrict__ A,
                                                    const float* __restrict__ B,
                                                    ushort* __restrict__ C) {
    __shared__ float sA[32 * 33];
    __shared__ float sB[32 * 64];
    gemm_body<64>(A, B, C, blockIdx.x, N_NODES, sA, sB);
}

// agg1: one WAVE per node (4 nodes per 256-block). Lane l owns channels
// 2l,2l+1 packed as one uint (bf16x2) -> one dword gather per edge per wave.
// Edge (src,nrm) broadcast via __shfl from a coalesced epack load. No LDS,
// no __syncthreads. out = relu(sum nrm_j*xw[s_j] + dinv^2*xw[node] + b).
__global__ __launch_bounds__(256) void agg1_kernel(const ushort* __restrict__ xwb,
                                                   const ull* __restrict__ epack,
                                                   const int* __restrict__ cnt_arr,
                                                   const float* __restrict__ dinv,
                                                   const float* __restrict__ bias,
                                                   float* __restrict__ out) {
    const uint* __restrict__ xw32 = (const uint*)xwb;   // row = 64 uints
    int w = threadIdx.x >> 6;
    int l = threadIdx.x & 63;
    int node = blockIdx.x * 4 + w;
    int cnt = cnt_arr[node];
    if (cnt > ELLW) cnt = ELLW;
    float dn = dinv[node];
    uint su = xw32[node * 64 + l];
    float acc0 = dn * dn * bf_lo(su);
    float acc1 = dn * dn * bf_hi(su);
    const ull* ep = epack + (long)node * ELLW;
    for (int b = 0; b < cnt; b += 64) {
        int m = cnt - b;
        if (m > 64) m = 64;
        ull v = (l < m) ? ep[b + l] : 0ULL;          // pad: nrm=0 -> no-op terms
        int sl = (int)(uint)(v & 0xffffffffULL);
        float nl = __uint_as_float((uint)(v >> 32));
#pragma unroll 4
        for (int j = 0; j < m; ++j) {
            int s = __shfl(sl, j);
            float n = __shfl(nl, j);
            uint u = xw32[s * 64 + l];
            acc0 = fmaf(n, bf_lo(u), acc0);
            acc1 = fmaf(n, bf_hi(u), acc1);
        }
    }
    float2 bb = ((const float2*)bias)[l];
    float2 o;
    o.x = fmaxf(acc0 + bb.x, 0.0f);
    o.y = fmaxf(acc1 + bb.y, 0.0f);
    ((float2*)out)[node * 64 + l] = o;
}

// agg2 (C=64, no relu): one wave per node; half-wave p handles edge 2i+p,
// lanes q<32 own channels 2q,2q+1. Zero-padded lanes make odd tails
// branchless; cross-half reduction via shfl_xor(32).
__global__ __launch_bounds__(256) void agg2_kernel(const ushort* __restrict__ xwb,
                                                   const ull* __restrict__ epack,
                                                   const int* __restrict__ cnt_arr,
                                                   const float* __restrict__ dinv,
                                                   const float* __restrict__ bias,
                                                   float* __restrict__ out) {
    const uint* __restrict__ xw32 = (const uint*)xwb;   // row = 32 uints
    int w = threadIdx.x >> 6;
    int lane = threadIdx.x & 63;
    int p = lane >> 5;
    int q = lane & 31;
    int node = blockIdx.x * 4 + w;
    int cnt = cnt_arr[node];
    if (cnt > ELLW) cnt = ELLW;
    float dn = dinv[node];
    float acc0 = 0.0f, acc1 = 0.0f;
    if (p == 0) {                                    // self-loop counted once
        uint su = xw32[node * 32 + q];
        acc0 = dn * dn * bf_lo(su);
        acc1 = dn * dn * bf_hi(su);
    }
    const ull* ep = epack + (long)node * ELLW;
    for (int b = 0; b < cnt; b += 64) {
        int m = cnt - b;
        if (m > 64) m = 64;
        ull v = (lane < m) ? ep[b + lane] : 0ULL;    // pad: nrm=0
        int sl = (int)(uint)(v & 0xffffffffULL);
        float nl = __uint_as_float((uint)(v >> 32));
        int iters = (m + 1) >> 1;
#pragma unroll 4
        for (int i = 0; i < iters; ++i) {
            int j = 2 * i + p;                       // j<=m<=64-1 lane idx safe
            int s = __shfl(sl, j);
            float n = __shfl(nl, j);                 // j==m -> n=0 (pad lane)
            uint u = xw32[s * 32 + q];
            acc0 = fmaf(n, bf_lo(u), acc0);
            acc1 = fmaf(n, bf_hi(u), acc1);
        }
    }
    acc0 += __shfl_xor(acc0, 32);
    acc1 += __shfl_xor(acc1, 32);
    if (p == 0) {
        float2 bb = ((const float2*)bias)[q];
        float2 o;
        o.x = acc0 + bb.x;
        o.y = acc1 + bb.y;
        ((float2*)out)[node * 32 + q] = o;
    }
}

extern "C" void kernel_launch(void* const* d_in, const int* in_sizes, int n_in,
                              void* d_out, int out_size, void* d_ws, size_t ws_size,
                              hipStream_t stream) {
    const float* x  = (const float*)d_in[0];
    const int*   ei = (const int*)d_in[1];
    const float* ew = (const float*)d_in[2];
    const float* W1 = (const float*)d_in[3];
    const float* b1 = (const float*)d_in[4];
    const float* W2 = (const float*)d_in[5];
    const float* b2 = (const float*)d_in[6];
    float* out = (float*)d_out;

    char* ws = (char*)d_ws;
    ushort* xw1b    = (ushort*)(ws + 0);
    float*  h       = (float*) (ws + 2560000);
    ushort* xw2b    = (ushort*)(ws + 7680000);
    ull*    epack   = (ull*)   (ws + 8960000);
    uint*   blockcnt= (uint*)  (ws + 24320000);
    uchar*  base8   = (uchar*) (ws + 29440000);
    uchar*  rank8   = (uchar*) (ws + 30720000);
    uint*   sd32    = (uint*)  (ws + 31360000);
    int*    cnt_arr = (int*)   (ws + 33920000);
    float*  dinv    = (float*) (ws + 33960000);

    preA_gemm1_kernel<<<CHUNKS + GB, 256, 0, stream>>>(ei, ew, rank8, sd32, blockcnt, x, W1, xw1b);
    scanB_kernel<<<(N_NODES + 255) / 256, 256, 0, stream>>>(blockcnt, base8, cnt_arr, dinv);
    fillC_kernel<<<CHUNKS * FILL_SPLIT, 256, 0, stream>>>(sd32, ew, rank8, base8, dinv, epack);
    agg1_kernel<<<N_NODES / 4, 256, 0, stream>>>(xw1b, epack, cnt_arr, dinv, b1, h);
    gemm2_kernel<<<GB, 256, 0, stream>>>(h, W2, xw2b);
    agg2_kernel<<<N_NODES / 4, 256, 0, stream>>>(xw2b, epack, cnt_arr, dinv, b2, out);
}

// Round 8
// 167.876 us; speedup vs baseline: 1.1172x; 1.1172x over previous
//
#include <hip/hip_runtime.h>
#include <math.h>

#define N_NODES 10000
#define N_EDGES 640000
#define K_DIM   128     // IN_CH == HID == 128
#define OUT_CH  64
#define ELLW    192     // max in-degree slots; Poisson(64) max ~110, P[>192]~1e-19

#define CHUNKS  128
#define CHUNK_E 5000    // N_EDGES / CHUNKS exactly
#define GB      313     // ceil(10000/32) gemm blocks

typedef unsigned long long ull;
typedef unsigned int uint;
typedef unsigned short ushort;
typedef unsigned char uchar;

#define FIXED_SCALE 262144.0f   // 2^18; count<<24 | fixed18(sum_w)

// ---------------- workspace layout (bytes) ----------------
// xw1b     : N*128 bf16   @ 0            (2,560,000)
// h        : N*128 f32    @  2,560,000   (5,120,000)
// xw2b     : N*64  bf16   @  7,680,000   (1,280,000)
// epack    : N*ELLW ull   @  8,960,000   (15,360,000)  (nrm_bits<<32 | src)
// blockcnt : CHUNKS*N u32 @ 24,320,000   (5,120,000)   (cnt<<24 | fixed18(sum_w))
// base8    : CHUNKS*N u8  @ 29,440,000   (1,280,000)
// rank8    : E u8         @ 30,720,000   (640,000)
// sd32     : E u32        @ 31,360,000   (2,560,000)   (dst<<16 | src)
// cnt_arr  : N int        @ 33,920,000   (40,000)
// dinv     : N f32        @ 33,960,000   (40,000)

__device__ __forceinline__ float bf_lo(uint u) {        // channel 2l (low ushort)
    return __uint_as_float(u << 16);
}
__device__ __forceinline__ float bf_hi(uint u) {        // channel 2l+1 (high ushort)
    return __uint_as_float(u & 0xffff0000u);
}
__device__ __forceinline__ ushort f2bf(float v) {
    uint u = __float_as_uint(v);
    uint r = u + 0x7fffu + ((u >> 16) & 1u);   // round-to-nearest-even
    return (ushort)(r >> 16);
}

// GEMM body: C_bf16[M,NCOL] = A[M,128] @ B[128,NCOL], fp32 accumulate.
template <int NCOL>
__device__ void gemm_body(const float* __restrict__ A, const float* __restrict__ B,
                          ushort* __restrict__ C, int blk, int M,
                          float* sA /*[32][33]*/, float* sB /*[32][NCOL]*/) {
    constexpr int K = 128;
    constexpr int TM = 32;
    constexpr int KT = 32;
    constexpr int R = 256 / NCOL;   // 2 (NCOL=128) or 4 (NCOL=64)
    constexpr int RPT = TM / R;     // 16 or 8
    int tid = threadIdx.x;
    int c = tid % NCOL;
    int rr = tid / NCOL;
    int row0 = blk * TM;
    float acc[RPT];
#pragma unroll
    for (int r = 0; r < RPT; ++r) acc[r] = 0.0f;

    for (int k0 = 0; k0 < K; k0 += KT) {
        for (int i = tid; i < TM * KT; i += 256) {
            int r = i / KT, k = i % KT;
            int gr = row0 + r;
            sA[r * (KT + 1) + k] = (gr < M) ? A[gr * K + k0 + k] : 0.0f;
        }
        for (int i = tid; i < KT * NCOL; i += 256) {
            int k = i / NCOL, cc = i % NCOL;
            sB[k * NCOL + cc] = B[(k0 + k) * NCOL + cc];
        }
        __syncthreads();
#pragma unroll
        for (int k = 0; k < KT; ++k) {
            float b = sB[k * NCOL + c];
#pragma unroll
            for (int r = 0; r < RPT; ++r)
                acc[r] += sA[(rr * RPT + r) * (KT + 1) + k] * b;
        }
        __syncthreads();
    }
#pragma unroll
    for (int r = 0; r < RPT; ++r) {
        int gr = row0 + rr * RPT + r;
        if (gr < M) C[gr * NCOL + c] = f2bf(acc[r]);
    }
}

// Kernel A. Blocks [0,CHUNKS): per-chunk u32 LDS counting histogram (no global
// atomics). Blocks [CHUNKS,..): gemm1 overlapped in the same launch.
__global__ __launch_bounds__(256) void preA_gemm1_kernel(const int* __restrict__ ei,
                                                         const float* __restrict__ ew,
                                                         uchar* __restrict__ rank8,
                                                         uint* __restrict__ sd32,
                                                         uint* __restrict__ blockcnt,
                                                         const float* __restrict__ x,
                                                         const float* __restrict__ W1,
                                                         ushort* __restrict__ xw1b) {
    __shared__ uint smem[N_NODES];   // 40 KB; gemm blocks overlay sA/sB here
    if (blockIdx.x < CHUNKS) {
        const int c = blockIdx.x;
        const int tid = threadIdx.x;
        __shared__ int sflag;
        if (tid == 0) sflag = 0;
        for (int i = tid; i < N_NODES; i += 256) smem[i] = 0u;
        __syncthreads();
        int a = (tid < 64) ? ei[2 * (c * CHUNK_E + tid) + 1] : 0;
        if (a) atomicOr(&sflag, 1);
        __syncthreads();
        const int f = sflag;                     // 1 => int32 layout
        const ull* ei64 = (const ull*)ei;
        for (int k = tid; k < CHUNK_E; k += 256) {
            int e = c * CHUNK_E + k;
            int s, d;
            if (f) { s = ei[e];        d = ei[N_EDGES + e]; }
            else   { s = (int)ei64[e]; d = (int)ei64[N_EDGES + e]; }
            float w = ew[e];
            uint fx = (uint)(w * FIXED_SCALE + 0.5f);
            uint old = atomicAdd(&smem[d], (1u << 24) | fx);
            rank8[e] = (uchar)(old >> 24);
            sd32[e] = ((uint)d << 16) | (uint)s;
        }
        __syncthreads();
        for (int i = tid; i < N_NODES; i += 256)
            blockcnt[c * N_NODES + i] = smem[i];
    } else {
        float* sA = (float*)smem;
        float* sB = sA + 32 * 33;
        gemm_body<128>(x, W1, xw1b, blockIdx.x - CHUNKS, N_NODES, sA, sB);
    }
}

// Kernel B: thread-per-node serial scan over the 128 chunk histograms.
__global__ __launch_bounds__(256) void scanB_kernel(const uint* __restrict__ blockcnt,
                                                    uchar* __restrict__ base8,
                                                    int* __restrict__ cnt_arr,
                                                    float* __restrict__ dinv) {
    int n = blockIdx.x * 256 + threadIdx.x;
    if (n >= N_NODES) return;
    uint wsum = 0;
    int run = 0;
#pragma unroll 8
    for (int c = 0; c < CHUNKS; ++c) {
        uint v = blockcnt[c * N_NODES + n];
        base8[c * N_NODES + n] = (uchar)run;
        run += (int)(v >> 24);
        wsum += v & 0xffffffu;
    }
    cnt_arr[n] = run;
    float dg = 1.0f + (float)wsum * (1.0f / FIXED_SCALE);
    dinv[n] = (float)(1.0 / sqrt((double)dg));
}

// Kernel C: atomic-free ELL fill. slot = base8[chunk][dst] + rank8[e].
#define FILL_SPLIT 4
#define FILL_PART  (CHUNK_E / FILL_SPLIT)   // 1250
__global__ __launch_bounds__(256) void fillC_kernel(const uint* __restrict__ sd32,
                                                    const float* __restrict__ ew,
                                                    const uchar* __restrict__ rank8,
                                                    const uchar* __restrict__ base8,
                                                    const float* __restrict__ dinv,
                                                    ull* __restrict__ epack) {
    const int c = blockIdx.x / FILL_SPLIT;
    const int p = blockIdx.x % FILL_SPLIT;
    const int k0 = p * FILL_PART;
    for (int k = k0 + threadIdx.x; k < k0 + FILL_PART; k += 256) {
        int e = c * CHUNK_E + k;
        uint sd = sd32[e];
        int s = (int)(sd & 0xffffu);
        int d = (int)(sd >> 16);
        float nrm = dinv[s] * ew[e] * dinv[d];
        int slot = (int)base8[c * N_NODES + d] + (int)rank8[e];
        if (slot < ELLW)
            epack[d * ELLW + slot] = ((ull)__float_as_uint(nrm) << 32) | (ull)(uint)s;
    }
}

__global__ __launch_bounds__(256) void gemm2_kernel(const float* __restrict__ A,
                                                    const float* __restrict__ B,
                                                    ushort* __restrict__ C) {
    __shared__ float sA[32 * 33];
    __shared__ float sB[32 * 64];
    gemm_body<64>(A, B, C, blockIdx.x, N_NODES, sA, sB);
}

// agg1: ONE WAVE (block=64) per node. node=blockIdx.x is workgroup-uniform,
// cnt forced scalar via readfirstlane -> uniform edge loop; ep[j] is a
// uniform-address load (1 line, L1-broadcast), independent across j and
// pipelined by unroll. Lane l owns channels 2l,2l+1 (bf16x2 dword gather,
// 256 B/wave coalesced). No LDS, no shuffles, no barriers.
__global__ __launch_bounds__(64) void agg1_kernel(const ushort* __restrict__ xwb,
                                                  const ull* __restrict__ epack,
                                                  const int* __restrict__ cnt_arr,
                                                  const float* __restrict__ dinv,
                                                  const float* __restrict__ bias,
                                                  float* __restrict__ out) {
    const uint* __restrict__ xw32 = (const uint*)xwb;   // row = 64 uints
    int node = blockIdx.x;
    int l = threadIdx.x;
    int cnt = __builtin_amdgcn_readfirstlane(cnt_arr[node]);
    if (cnt > ELLW) cnt = ELLW;
    float dn = dinv[node];
    float d2 = dn * dn;
    uint su = xw32[node * 64 + l];
    float acc0 = d2 * bf_lo(su);
    float acc1 = d2 * bf_hi(su);
    const ull* ep = epack + (long)node * ELLW;
#pragma unroll 8
    for (int j = 0; j < cnt; ++j) {
        ull v = ep[j];                               // uniform address
        uint s = (uint)v;                            // low 32 = src (<10000)
        float n = __uint_as_float((uint)(v >> 32));
        uint u = xw32[s * 64 + l];                   // 256 B coalesced gather
        acc0 = fmaf(n, bf_lo(u), acc0);
        acc1 = fmaf(n, bf_hi(u), acc1);
    }
    float2 bb = ((const float2*)bias)[l];
    float2 o;
    o.x = fmaxf(acc0 + bb.x, 0.0f);
    o.y = fmaxf(acc1 + bb.y, 0.0f);
    ((float2*)out)[node * 64 + l] = o;
}

// agg2 (C=64, no relu): one wave per TWO nodes. Lanes 0-31 serve node A,
// lanes 32-63 node B (q = lane&31 owns channels 2q,2q+1). Per j: two
// uniform-address edge loads (epA[j], epB[j]), per-lane select, one 256 B
// gather covering both rows. Tail edges (j >= cnt of own node) get n=0 and
// poison src clamped to 16 bits (address stays inside workspace).
__global__ __launch_bounds__(64) void agg2_kernel(const ushort* __restrict__ xwb,
                                                  const ull* __restrict__ epack,
                                                  const int* __restrict__ cnt_arr,
                                                  const float* __restrict__ dinv,
                                                  const float* __restrict__ bias,
                                                  float* __restrict__ out) {
    const uint* __restrict__ xw32 = (const uint*)xwb;   // row = 32 uints
    int A = blockIdx.x * 2;
    int B = A + 1;
    int lane = threadIdx.x;
    int half = lane >> 5;
    int q = lane & 31;
    int cntA = __builtin_amdgcn_readfirstlane(cnt_arr[A]);
    int cntB = __builtin_amdgcn_readfirstlane(cnt_arr[B]);
    if (cntA > ELLW) cntA = ELLW;
    if (cntB > ELLW) cntB = ELLW;
    float dnA = dinv[A], dnB = dinv[B];
    int myn = half ? B : A;
    int mycnt = half ? cntB : cntA;
    float dn = half ? dnB : dnA;
    float d2 = dn * dn;
    uint su = xw32[myn * 32 + q];
    float acc0 = d2 * bf_lo(su);
    float acc1 = d2 * bf_hi(su);
    const ull* epA = epack + (long)A * ELLW;
    const ull* epB = epack + (long)B * ELLW;
    int mx = cntA > cntB ? cntA : cntB;
#pragma unroll 4
    for (int j = 0; j < mx; ++j) {
        ull vA = epA[j];                             // uniform address
        ull vB = epB[j];                             // uniform address
        ull v = half ? vB : vA;
        uint s = (uint)v & 0xffffu;                  // clamp poison tails
        float n = (j < mycnt) ? __uint_as_float((uint)(v >> 32)) : 0.0f;
        uint u = xw32[s * 32 + q];                   // 256 B across both rows
        acc0 = fmaf(n, bf_lo(u), acc0);
        acc1 = fmaf(n, bf_hi(u), acc1);
    }
    float2 bb = ((const float2*)bias)[q];
    float2 o;
    o.x = acc0 + bb.x;
    o.y = acc1 + bb.y;
    ((float2*)out)[myn * 32 + q] = o;
}

extern "C" void kernel_launch(void* const* d_in, const int* in_sizes, int n_in,
                              void* d_out, int out_size, void* d_ws, size_t ws_size,
                              hipStream_t stream) {
    const float* x  = (const float*)d_in[0];
    const int*   ei = (const int*)d_in[1];
    const float* ew = (const float*)d_in[2];
    const float* W1 = (const float*)d_in[3];
    const float* b1 = (const float*)d_in[4];
    const float* W2 = (const float*)d_in[5];
    const float* b2 = (const float*)d_in[6];
    float* out = (float*)d_out;

    char* ws = (char*)d_ws;
    ushort* xw1b    = (ushort*)(ws + 0);
    float*  h       = (float*) (ws + 2560000);
    ushort* xw2b    = (ushort*)(ws + 7680000);
    ull*    epack   = (ull*)   (ws + 8960000);
    uint*   blockcnt= (uint*)  (ws + 24320000);
    uchar*  base8   = (uchar*) (ws + 29440000);
    uchar*  rank8   = (uchar*) (ws + 30720000);
    uint*   sd32    = (uint*)  (ws + 31360000);
    int*    cnt_arr = (int*)   (ws + 33920000);
    float*  dinv    = (float*) (ws + 33960000);

    preA_gemm1_kernel<<<CHUNKS + GB, 256, 0, stream>>>(ei, ew, rank8, sd32, blockcnt, x, W1, xw1b);
    scanB_kernel<<<(N_NODES + 255) / 256, 256, 0, stream>>>(blockcnt, base8, cnt_arr, dinv);
    fillC_kernel<<<CHUNKS * FILL_SPLIT, 256, 0, stream>>>(sd32, ew, rank8, base8, dinv, epack);
    agg1_kernel<<<N_NODES, 64, 0, stream>>>(xw1b, epack, cnt_arr, dinv, b1, h);
    gemm2_kernel<<<GB, 256, 0, stream>>>(h, W2, xw2b);
    agg2_kernel<<<N_NODES / 2, 64, 0, stream>>>(xw2b, epack, cnt_arr, dinv, b2, out);
}